// Round 10
// baseline (3582.486 us; speedup 1.0000x reference)
//
#include <hip/hip_runtime.h>

// ---------------------------------------------------------------------------
// AlternatingHGN: RELS={(0,1),(1,2),(0,2)}, NE=100000 each, NNZ=500000,
// C_IN=16, EMB=WIDTH=64, OUT=16.
//
// R9 design: CSR/CSC gather-pool (no fp32 atomic scatter, no pool tables):
//  - per-role CSR build: counts -> block scan -> fill (colv = other-side idx,
//    nid = nnz id). Indices static across layers -> built once per call.
//  - L1: fused pool(vals)+matmul+relu+BNstats per entity -> emb1 (bf16)
//  - embW tables (BN folded into weights) -> tbl (bf16)
//  - L2: fused pool(relu(self+other[colv]))+matmul+relu+stats -> emb2 (bf16)
//  - final: fused pool+64x16 matmul -> out (direct store, no atomics)
// ---------------------------------------------------------------------------

#define NE_  100000
#define NNZ_ 500000

__device__ __forceinline__ ushort f2bf(float x) {
    uint32_t u = __float_as_uint(x);
    u += 0x7fffu + ((u >> 16) & 1u);
    return (ushort)(u >> 16);
}
__device__ __forceinline__ float bf2f(ushort h) {
    return __uint_as_float(((uint32_t)h) << 16);
}

// ------------------------------ kernels ------------------------------------

__global__ __launch_bounds__(256)
void count_kernel(const int* __restrict__ row, const int* __restrict__ col,
                  int* __restrict__ cntR, int* __restrict__ cntC)
{
    int g = blockIdx.x * 256 + threadIdx.x;
    if (g < NNZ_) {
        atomicAdd(&cntR[row[g]], 1);
        atomicAdd(&cntC[col[g]], 1);
    }
}

__global__ __launch_bounds__(256)
void inv_kernel(const int* __restrict__ cnt, float* __restrict__ icnt, int n)
{
    int g = blockIdx.x * 256 + threadIdx.x;
    if (g < n) icnt[g] = 1.f / fmaxf((float)cnt[g], 1.f);
}

// one block per role: exclusive scan of cnt -> offs[NE_+1], copy to cursor
__global__ __launch_bounds__(1024)
void scan_kernel(const int* __restrict__ cnt, int* __restrict__ offs,
                 int* __restrict__ cursor)
{
    __shared__ int s[1024];
    __shared__ int carry_s;
    int k = blockIdx.x, t = threadIdx.x;
    const int* c = cnt + (size_t)k * NE_;
    int* o = offs + (size_t)k * (NE_ + 1);
    int* cur = cursor + (size_t)k * NE_;
    if (t == 0) carry_s = 0;
    __syncthreads();
    for (int base = 0; base < NE_; base += 1024) {
        int i = base + t;
        int v = (i < NE_) ? c[i] : 0;
        s[t] = v;
        __syncthreads();
        for (int off = 1; off < 1024; off <<= 1) {
            int x = (t >= off) ? s[t - off] : 0;
            __syncthreads();
            s[t] += x;
            __syncthreads();
        }
        int excl = s[t] - v;
        int cb = carry_s;
        if (i < NE_) { o[i] = cb + excl; cur[i] = cb + excl; }
        __syncthreads();
        if (t == 1023) carry_s = cb + s[1023];
        __syncthreads();
    }
    if (t == 0) o[NE_] = carry_s;
}

__global__ __launch_bounds__(256)
void fill_kernel(const int* __restrict__ row, const int* __restrict__ col,
                 int* __restrict__ curR, int* __restrict__ curC,
                 int* __restrict__ colvR, int* __restrict__ nidR,
                 int* __restrict__ colvC, int* __restrict__ nidC)
{
    int n = blockIdx.x * 256 + threadIdx.x;
    if (n < NNZ_) {
        int i = row[n], j = col[n];
        int p = atomicAdd(&curR[i], 1);
        colvR[p] = j; nidR[p] = n;
        int q = atomicAdd(&curC[j], 1);
        colvC[q] = i; nidC[q] = n;
    }
}

// L1 fused pool+matmul: wave = 2 entities; 16-lane groups pool (entity,role)
// vals sums; 16-step shfl chain does (sumA*icA)@pwA + (sumB*icB)@pwB;
// relu + BN stats + bf16 store.
__global__ __launch_bounds__(256)
void l1emb_kernel(const int* __restrict__ offsA, const int* __restrict__ nidA,
                  const float* __restrict__ valsA, const float* __restrict__ icA,
                  const int* __restrict__ offsB, const int* __restrict__ nidB,
                  const float* __restrict__ valsB, const float* __restrict__ icB,
                  const float* __restrict__ pwA, const float* __restrict__ pwB,
                  ushort* __restrict__ emb, float* __restrict__ stats)
{
    __shared__ float2 w[16 * 64];     // 8 KB (wA, wB)
    __shared__ float red[2][256];
    int t = threadIdx.x;
    for (int i = t; i < 1024; i += 256) w[i] = make_float2(pwA[i], pwB[i]);
    __syncthreads();
    int lane = t & 63, sub = t >> 6;
    int grp = lane >> 4, l16 = lane & 15;
    int e0 = (blockIdx.x * 4 + sub) * 2;          // 12500*4*2 = 100000 exact
    int eg = e0 + (grp >> 1);
    bool roleB = (grp & 1);
    const int* offs = roleB ? offsB : offsA;
    const int* nid  = roleB ? nidB : nidA;
    const float* vals = roleB ? valsB : valsA;
    float ic = roleB ? icB[eg] : icA[eg];
    int p0 = offs[eg], p1 = offs[eg + 1];
    float sum = 0.f;
    for (int p = p0; p < p1; ++p) {
        int n = nid[p];
        sum += vals[(size_t)n * 16 + l16];
    }
    sum *= ic;
    float acc0 = 0.f, acc1 = 0.f;
#pragma unroll
    for (int c = 0; c < 16; ++c) {
        float a0 = __shfl(sum, c);
        float b0 = __shfl(sum, 16 + c);
        float a1 = __shfl(sum, 32 + c);
        float b1 = __shfl(sum, 48 + c);
        float2 ww = w[c * 64 + lane];
        acc0 += a0 * ww.x + b0 * ww.y;
        acc1 += a1 * ww.x + b1 * ww.y;
    }
    float x0 = fmaxf(acc0, 0.f), x1 = fmaxf(acc1, 0.f);
    emb[(size_t)e0 * 64 + lane] = f2bf(x0);
    emb[(size_t)(e0 + 1) * 64 + lane] = f2bf(x1);
    red[0][t] = x0 + x1; red[1][t] = x0 * x0 + x1 * x1;
    __syncthreads();
    if (t < 64) {
        float rs = red[0][t] + red[0][64 + t] + red[0][128 + t] + red[0][192 + t];
        float rq = red[1][t] + red[1][64 + t] + red[1][128 + t] + red[1][192 + t];
        atomicAdd(&stats[t], rs);
        atomicAdd(&stats[64 + t], rq);
    }
}

// pooled 64-vec for one entity/role: sum over segment of relu(self + oth[colv])
__device__ __forceinline__ float pool64(const int* __restrict__ offs,
                                        const int* __restrict__ colv,
                                        const ushort* __restrict__ selfT,
                                        const ushort* __restrict__ oth,
                                        int e, int lane)
{
    int p0 = offs[e], p1 = offs[e + 1];
    float self = bf2f(selfT[(size_t)e * 64 + lane]);
    float s = 0.f;
    int p = p0;
    for (; p + 1 < p1; p += 2) {
        int ca = colv[p], cb = colv[p + 1];
        float va = fmaxf(self + bf2f(oth[(size_t)ca * 64 + lane]), 0.f);
        float vb = fmaxf(self + bf2f(oth[(size_t)cb * 64 + lane]), 0.f);
        s += va + vb;
    }
    if (p < p1) {
        int ca = colv[p];
        s += fmaxf(self + bf2f(oth[(size_t)ca * 64 + lane]), 0.f);
    }
    return s;
}

// L2 fused pool+matmul: wave = 2 entities; pool both roles; 64-step chain
// with bf16-packed weights; relu + stats + bf16 store.
__global__ __launch_bounds__(256)
void l2emb_kernel(const int* __restrict__ offsA, const int* __restrict__ colvA,
                  const float* __restrict__ icA,
                  const ushort* __restrict__ selfA, const ushort* __restrict__ othA,
                  const float* __restrict__ pwA,
                  const int* __restrict__ offsB, const int* __restrict__ colvB,
                  const float* __restrict__ icB,
                  const ushort* __restrict__ selfB, const ushort* __restrict__ othB,
                  const float* __restrict__ pwB,
                  ushort* __restrict__ emb, float* __restrict__ stats)
{
    __shared__ ushort2 w[64 * 64];    // 16 KB (bf16 wA, bf16 wB)
    __shared__ float red[2][256];
    int t = threadIdx.x;
    for (int i = t; i < 4096; i += 256)
        w[i] = make_ushort2(f2bf(pwA[i]), f2bf(pwB[i]));
    __syncthreads();
    int lane = t & 63, sub = t >> 6;
    int e0 = (blockIdx.x * 4 + sub) * 2, e1 = e0 + 1;
    float vA0 = pool64(offsA, colvA, selfA, othA, e0, lane) * icA[e0];
    float vB0 = pool64(offsB, colvB, selfB, othB, e0, lane) * icB[e0];
    float vA1 = pool64(offsA, colvA, selfA, othA, e1, lane) * icA[e1];
    float vB1 = pool64(offsB, colvB, selfB, othB, e1, lane) * icB[e1];
    float acc0 = 0.f, acc1 = 0.f;
#pragma unroll
    for (int k = 0; k < 64; ++k) {
        float a0 = __shfl(vA0, k), b0 = __shfl(vB0, k);
        float a1 = __shfl(vA1, k), b1 = __shfl(vB1, k);
        ushort2 wp = w[k * 64 + lane];
        float wA = bf2f(wp.x), wB = bf2f(wp.y);
        acc0 += a0 * wA + b0 * wB;
        acc1 += a1 * wA + b1 * wB;
    }
    float x0 = fmaxf(acc0, 0.f), x1 = fmaxf(acc1, 0.f);
    emb[(size_t)e0 * 64 + lane] = f2bf(x0);
    emb[(size_t)e1 * 64 + lane] = f2bf(x1);
    red[0][t] = x0 + x1; red[1][t] = x0 * x0 + x1 * x1;
    __syncthreads();
    if (t < 64) {
        float rs = red[0][t] + red[0][64 + t] + red[0][128 + t] + red[0][192 + t];
        float rq = red[1][t] + red[1][64 + t] + red[1][128 + t] + red[1][192 + t];
        atomicAdd(&stats[t], rs);
        atomicAdd(&stats[64 + t], rq);
    }
}

// embW = bn(emb) @ bw with BN folded (w''=bw/sigma, bias=-mu@w''); bf16 in/out
__global__ __launch_bounds__(256)
void embwb_kernel(const ushort* __restrict__ emb, const float* __restrict__ stats,
                  const float* __restrict__ bw, ushort* __restrict__ out)
{
    __shared__ float w[64 * 64];
    __shared__ float bias[64], invs[64], mu[64];
    __shared__ float rows[8][64];
    int t = threadIdx.x;
    if (t < 64) {
        float s = stats[t], q = stats[64 + t];
        float m = s * (1.f / (float)NE_);
        float v = q * (1.f / (float)NE_) - m * m;
        mu[t] = m;
        invs[t] = rsqrtf(v + 1e-5f);
    }
    __syncthreads();
    for (int i = t; i < 64 * 64; i += 256) w[i] = bw[i] * invs[i >> 6];
    __syncthreads();
    if (t < 64) {
        float b = 0.f;
        for (int k = 0; k < 64; ++k) b -= mu[k] * w[k * 64 + t];
        bias[t] = b;
    }
    int f = t & 63, sub = t >> 6;
    size_t base = (size_t)blockIdx.x * 32;    // 3125 blocks x 32 rows
    for (int it = 0; it < 32; it += 8) {
        __syncthreads();
        for (int i = t; i < 512; i += 256) {
            size_t rr = base + it + (i >> 6);
            rows[i >> 6][i & 63] = bf2f(emb[rr * 64 + (i & 63)]);
        }
        __syncthreads();
        size_t rr0 = base + it + sub;
        size_t rr1 = rr0 + 4;
        float a0 = bias[f], a1 = bias[f];
#pragma unroll
        for (int k = 0; k < 64; ++k) {
            float wkf = w[k * 64 + f];
            a0 += rows[sub][k] * wkf;
            a1 += rows[sub + 4][k] * wkf;
        }
        out[rr0 * 64 + f] = f2bf(a0);
        out[rr1 * 64 + f] = f2bf(a1);
    }
}

// final: entity-0 rows of rel0 + rel2: pool both roles, (pool*ic)@w (64x16),
// k-split chains + shfl_xor reduce; direct store to out.
__global__ __launch_bounds__(256)
void final_kernel(const int* __restrict__ offs0, const int* __restrict__ colv0,
                  const float* __restrict__ ic0t,
                  const ushort* __restrict__ self0, const ushort* __restrict__ oth0,
                  const int* __restrict__ offs4, const int* __restrict__ colv4,
                  const float* __restrict__ ic4t,
                  const ushort* __restrict__ self4, const ushort* __restrict__ oth4,
                  const float* __restrict__ w0g, const float* __restrict__ w4g,
                  float* __restrict__ out)
{
    __shared__ float2 w[64 * 16];     // 8 KB (w0, w4)
    int t = threadIdx.x;
    for (int i = t; i < 1024; i += 256) w[i] = make_float2(w0g[i], w4g[i]);
    __syncthreads();
    int lane = t & 63, sub = t >> 6;
    int e0 = (blockIdx.x * 4 + sub) * 2, e1 = e0 + 1;
    float p0a = pool64(offs0, colv0, self0, oth0, e0, lane) * ic0t[e0];
    float p4a = pool64(offs4, colv4, self4, oth4, e0, lane) * ic4t[e0];
    float p0b = pool64(offs0, colv0, self0, oth0, e1, lane) * ic0t[e1];
    float p4b = pool64(offs4, colv4, self4, oth4, e1, lane) * ic4t[e1];
    int g = lane >> 4, o = lane & 15;
    float a0 = 0.f, a1 = 0.f;
#pragma unroll
    for (int c = 0; c < 16; ++c) {
        int k = g * 16 + c;
        float s0 = __shfl(p0a, k), s4 = __shfl(p4a, k);
        float s0b = __shfl(p0b, k), s4b = __shfl(p4b, k);
        float2 ww = w[k * 16 + o];
        a0 += s0 * ww.x + s4 * ww.y;
        a1 += s0b * ww.x + s4b * ww.y;
    }
    a0 += __shfl_xor(a0, 16); a0 += __shfl_xor(a0, 32);
    a1 += __shfl_xor(a1, 16); a1 += __shfl_xor(a1, 32);
    if (lane < 16) {
        out[(size_t)e0 * 16 + lane] = a0;
        out[(size_t)e1 * 16 + lane] = a1;
    }
}

// ------------------------------ launch -------------------------------------

extern "C" void kernel_launch(void* const* d_in, const int* in_sizes, int n_in,
                              void* d_out, int out_size, void* d_ws, size_t ws_size,
                              hipStream_t stream)
{
    const float* vals[3] = { (const float*)d_in[0], (const float*)d_in[3], (const float*)d_in[6] };
    const int*   row[3]  = { (const int*)d_in[1], (const int*)d_in[4], (const int*)d_in[7] };
    const int*   col[3]  = { (const int*)d_in[2], (const int*)d_in[5], (const int*)d_in[8] };
    const float* pw0 = (const float*)d_in[9];
    const float* pw1 = (const float*)d_in[10];
    const float* pw2 = (const float*)d_in[11];
    const float* bw0 = (const float*)d_in[12];
    const float* bw1 = (const float*)d_in[13];
    float* out = (float*)d_out;

    // ---- workspace layout (148.8 MB) ----
    const size_t OFF_CNT   = 0;           // 6*NE int          2.400 MB
    const size_t OFF_ICNT  = 2400000;     // 6*NE f32          2.400 MB
    const size_t OFF_OFFS  = 4800000;     // 6*(NE+1) int      2.400 MB
    const size_t OFF_CUR   = 7200032;     // 6*NE int          2.400 MB
    const size_t OFF_STATS = 9600032;     // 6*128 f32         3 KB (pad 4 KB)
    const size_t OFF_COLV  = 9604128;     // 6*NNZ int        12.000 MB
    const size_t OFF_NID   = 21604128;    // 6*NNZ int        12.000 MB
    const size_t OFF_EMB   = 33604128;    // 3*NE*64 bf16     38.400 MB
    const size_t OFF_TBL   = 72004128;    // 6*NE*64 bf16     76.800 MB
    const size_t WS_NEED   = 148804128;

    if (ws_size < WS_NEED) {
        hipMemsetAsync(d_out, 0, (size_t)out_size * 4, stream);  // clean fail
        return;
    }

    char* ws = (char*)d_ws;
    int*    cnt   = (int*)(ws + OFF_CNT);
    float*  icnt  = (float*)(ws + OFF_ICNT);
    int*    offs  = (int*)(ws + OFF_OFFS);
    int*    cursor= (int*)(ws + OFF_CUR);
    float*  stats = (float*)(ws + OFF_STATS);
    int*    colv  = (int*)(ws + OFF_COLV);
    int*    nid   = (int*)(ws + OFF_NID);
    ushort* EMB   = (ushort*)(ws + OFF_EMB);
    ushort* TBL   = (ushort*)(ws + OFF_TBL);

    int *cnt6[6], *offs6[6], *cur6[6], *colv6[6], *nid6[6];
    float* ic6[6];
    for (int k = 0; k < 6; ++k) {
        cnt6[k]  = cnt + (size_t)k * NE_;
        ic6[k]   = icnt + (size_t)k * NE_;
        offs6[k] = offs + (size_t)k * (NE_ + 1);
        cur6[k]  = cursor + (size_t)k * NE_;
        colv6[k] = colv + (size_t)k * NNZ_;
        nid6[k]  = nid + (size_t)k * NNZ_;
    }
    ushort* emb3[3];
    for (int e = 0; e < 3; ++e) emb3[e] = EMB + (size_t)e * NE_ * 64;
    ushort* tbl[6];
    for (int k = 0; k < 6; ++k) tbl[k] = TBL + (size_t)k * NE_ * 64;

    // ---- CSR build (indices static across layers) ----
    hipMemsetAsync(cnt, 0, 2400000, stream);
    hipMemsetAsync(stats, 0, 3072, stream);
    for (int r = 0; r < 3; ++r)
        count_kernel<<<(NNZ_ + 255) / 256, 256, 0, stream>>>(row[r], col[r],
                                                             cnt6[2 * r], cnt6[2 * r + 1]);
    inv_kernel<<<(6 * NE_ + 255) / 256, 256, 0, stream>>>(cnt, icnt, 6 * NE_);
    scan_kernel<<<6, 1024, 0, stream>>>(cnt, offs, cursor);
    for (int r = 0; r < 3; ++r)
        fill_kernel<<<(NNZ_ + 255) / 256, 256, 0, stream>>>(row[r], col[r],
                                                            cur6[2 * r], cur6[2 * r + 1],
                                                            colv6[2 * r], nid6[2 * r],
                                                            colv6[2 * r + 1], nid6[2 * r + 1]);

    // ---- layer 1: fused pool+matmul per entity (roles: e0:{0,4} e1:{1,2} e2:{3,5}) ----
    l1emb_kernel<<<12500, 256, 0, stream>>>(offs6[0], nid6[0], vals[0], ic6[0],
                                            offs6[4], nid6[4], vals[2], ic6[4],
                                            pw0 + 0 * 1024, pw0 + 4 * 1024,
                                            emb3[0], stats + 0 * 128);
    l1emb_kernel<<<12500, 256, 0, stream>>>(offs6[1], nid6[1], vals[0], ic6[1],
                                            offs6[2], nid6[2], vals[1], ic6[2],
                                            pw0 + 1 * 1024, pw0 + 2 * 1024,
                                            emb3[1], stats + 1 * 128);
    l1emb_kernel<<<12500, 256, 0, stream>>>(offs6[3], nid6[3], vals[1], ic6[3],
                                            offs6[5], nid6[5], vals[2], ic6[5],
                                            pw0 + 3 * 1024, pw0 + 5 * 1024,
                                            emb3[2], stats + 2 * 128);

    // ---- embW1 tables (bf16), BN folded; table t source {0,1,1,2,0,2} ----
    {
        const int src[6] = { 0, 1, 1, 2, 0, 2 };
        for (int t = 0; t < 6; ++t)
            embwb_kernel<<<3125, 256, 0, stream>>>(emb3[src[t]], stats + src[t] * 128,
                                                   bw0 + (size_t)t * 4096, tbl[t]);
    }

    // ---- layer 2: fused pool+matmul per entity ----
    l2emb_kernel<<<12500, 256, 0, stream>>>(offs6[0], colv6[0], ic6[0], tbl[0], tbl[1],
                                            pw1 + (size_t)0 * 4096,
                                            offs6[4], colv6[4], ic6[4], tbl[4], tbl[5],
                                            pw1 + (size_t)4 * 4096,
                                            emb3[0], stats + 3 * 128);
    l2emb_kernel<<<12500, 256, 0, stream>>>(offs6[1], colv6[1], ic6[1], tbl[1], tbl[0],
                                            pw1 + (size_t)1 * 4096,
                                            offs6[2], colv6[2], ic6[2], tbl[2], tbl[3],
                                            pw1 + (size_t)2 * 4096,
                                            emb3[1], stats + 4 * 128);
    l2emb_kernel<<<12500, 256, 0, stream>>>(offs6[3], colv6[3], ic6[3], tbl[3], tbl[2],
                                            pw1 + (size_t)3 * 4096,
                                            offs6[5], colv6[5], ic6[5], tbl[5], tbl[4],
                                            pw1 + (size_t)5 * 4096,
                                            emb3[2], stats + 5 * 128);

    // ---- embW2 tables: slots {0,1,2,3} = {e0@bw1[0], e1@bw1[1], e0@bw1[4], e2@bw1[5]} ----
    embwb_kernel<<<3125, 256, 0, stream>>>(emb3[0], stats + 3 * 128,
                                           bw1 + (size_t)0 * 4096, tbl[0]);
    embwb_kernel<<<3125, 256, 0, stream>>>(emb3[1], stats + 4 * 128,
                                           bw1 + (size_t)1 * 4096, tbl[1]);
    embwb_kernel<<<3125, 256, 0, stream>>>(emb3[0], stats + 3 * 128,
                                           bw1 + (size_t)4 * 4096, tbl[2]);
    embwb_kernel<<<3125, 256, 0, stream>>>(emb3[2], stats + 5 * 128,
                                           bw1 + (size_t)5 * 4096, tbl[3]);

    // ---- final: entity0 rows of rel0 (pw2 tbl0) + rel2 (pw2 tbl4), direct out ----
    final_kernel<<<12500, 256, 0, stream>>>(offs6[0], colv6[0], ic6[0], tbl[0], tbl[1],
                                            offs6[4], colv6[4], ic6[4], tbl[2], tbl[3],
                                            pw2, pw2 + 4 * 1024, out);
}